// Round 5
// baseline (184.495 us; speedup 1.0000x reference)
//
#include <hip/hip_runtime.h>

// Problem constants (match reference setup_inputs)
constexpr int   B = 32, E = 64, H = 128, W = 128, R = 13, D = 32;
constexpr float GAIN = 2.0f, BASELINE = 100.0f;
constexpr int   HALF = R / 2;           // 6
constexpr int   PLANE = H * W;          // 16384 floats/plane

// native clang vector (works with __builtin_nontemporal_store, unlike HIP float4)
typedef float v4f __attribute__((ext_vector_type(4)));

// power v^p for p in 0..3, with 0^0 == 1
__device__ __forceinline__ float pw(float v, int p) {
    float r = 1.0f;
    if (p >= 1) r = v;
    if (p >= 2) r *= v;
    if (p >= 3) r *= v;
    return r;
}

// ---------------------------------------------------------------------------
// Single-pass fused renderer.
// Grid: B*E*4 blocks; block = (emitter be, quarter jb). Each block owns 32
// consecutive image rows of one emitter plane and writes them exactly once.
//
// JAX .at[rows,cols].add(patch, mode='drop') semantics: negative indices wrap
// (+size) then still-OOB dropped. Column wrap/drop handled at patch-scatter
// time into an expanded 13x128 LDS buffer; row wrap handled per streamed row.
// ---------------------------------------------------------------------------
__global__ __launch_bounds__(256)
void render_fused_kernel(const float* __restrict__ xyz,       // [B,E,3]
                         const float* __restrict__ n_photons, // [B,E]
                         const float* __restrict__ bg,        // [B,H,W]
                         const float* __restrict__ coeff,     // [D,R,R,4,4,4]
                         float* __restrict__ out)             // [B,E,H,W]
{
    const int blk = blockIdx.x;
    const int be  = blk >> 2;            // emitter id (0..2047)
    const int jb  = blk & 3;             // quarter of the plane
    const int b   = be >> 6;             // frame
    const int tid = threadIdx.x;
    const int base_row = jb << 5;        // 32 rows per block

    __shared__ float s_w[64];            // separable weights pz[a]*py[b]*px[c]
    __shared__ float s_row[R * W];       // expanded patch: [patch_row][image_col]

    // --- emitter parameters (broadcast loads; computed redundantly) ---
    const float x = xyz[be * 3 + 0];
    const float y = xyz[be * 3 + 1];
    const float z = xyz[be * 3 + 2];
    const float nph = n_photons[be];

    const float xf = floorf(x), yf = floorf(y);
    const float dx = x - xf,   dy = y - yf;
    float zc = fminf(fmaxf(z, 0.0f), (float)(D - 1) - 1e-6f);
    const float zf = floorf(zc);
    const int   zi = (int)zf;
    const float dz = zc - zf;

    const int r0 = (int)yf - HALF;       // patch-row 0's image row (may be <0)
    const int c0 = (int)xf - HALF;       // patch-col 0's image col (may be <0)

    // --- stage 1: zero expanded buffer + compute 64 separable weights ---
    #pragma unroll
    for (int i = tid; i < R * W; i += 256) s_row[i] = 0.0f;
    if (tid < 64) {
        const int a  = tid >> 4;
        const int bb = (tid >> 2) & 3;
        const int c  = tid & 3;
        s_w[tid] = pw(dz, a) * pw(dy, bb) * pw(dx, c);
    }
    __syncthreads();

    // --- stage 2: 169 patch pixels; scatter into expanded buffer with
    //     wrap/drop applied to the COLUMN here (row handled at stream time) ---
    if (tid < R * R) {
        const int pr = tid / R;
        const int pc = tid - pr * R;
        const float* cp = coeff + (((size_t)zi * R + pr) * R + pc) * 64;
        float acc = 0.0f;
        #pragma unroll
        for (int k = 0; k < 64; k += 4) {
            const v4f cc = *(const v4f*)(cp + k);
            acc += cc.x * s_w[k + 0];
            acc += cc.y * s_w[k + 1];
            acc += cc.z * s_w[k + 2];
            acc += cc.w * s_w[k + 3];
        }
        int col = c0 + pc;
        if (col < 0) col += W;           // JAX negative-index wrap
        if (col < W)                     // high side: dropped
            s_row[pr * W + col] = acc * nph;
    }
    __syncthreads();

    // --- stage 3: stream 32 rows, float4 per lane-iter, write-once ---
    const float* __restrict__ bgp  = bg  + ((size_t)b  << 14);
    float*       __restrict__ outp = out + ((size_t)be << 14);

    #pragma unroll
    for (int j = 0; j < 4; ++j) {
        const int i   = j * 256 + tid;       // float4 index within block chunk
        const int row = base_row + (i >> 5); // 32 float4 per row
        const int col = (i & 31) << 2;
        const size_t off = ((size_t)row << 7) + col;

        v4f v = *(const v4f*)(bgp + off);

        // patch-row lookup with JAX wrap: direct, else wrapped (row>=122)
        int pr = row - r0;
        if (pr < 0 || pr >= R) pr = row - r0 - 128;
        if (pr >= 0 && pr < R) {
            const v4f p = *(const v4f*)(s_row + pr * W + col);
            v += p;
        }

        v = v * GAIN + BASELINE;
        __builtin_nontemporal_store(v, (v4f*)(outp + off));
    }
}

extern "C" void kernel_launch(void* const* d_in, const int* in_sizes, int n_in,
                              void* d_out, int out_size, void* d_ws, size_t ws_size,
                              hipStream_t stream) {
    const float* xyz       = (const float*)d_in[0];  // [B,E,3]
    const float* n_photons = (const float*)d_in[1];  // [B,E]
    const float* bg        = (const float*)d_in[2];  // [B,H,W]
    const float* coeff     = (const float*)d_in[3];  // [D,R,R,4,4,4]
    float* out = (float*)d_out;                      // [B,E,H,W]

    // 4 blocks per emitter plane; every output byte written exactly once
    render_fused_kernel<<<dim3(B * E * 4), dim3(256), 0, stream>>>(
        xyz, n_photons, bg, coeff, out);
}

// Round 6
// 164.670 us; speedup vs baseline: 1.1204x; 1.1204x over previous
//
#include <hip/hip_runtime.h>

// Problem constants (match reference setup_inputs)
constexpr int   B = 32, E = 64, H = 128, W = 128, R = 13, D = 32;
constexpr float GAIN = 2.0f, BASELINE = 100.0f;
constexpr int   HALF = R / 2;           // 6
constexpr int   PLANE = H * W;          // 16384 floats/plane

typedef float v4f __attribute__((ext_vector_type(4)));

// power v^p for p in 0..3, with 0^0 == 1
__device__ __forceinline__ float pw(float v, int p) {
    float r = 1.0f;
    if (p >= 1) r = v;
    if (p >= 2) r *= v;
    if (p >= 3) r *= v;
    return r;
}

// ---------------------------------------------------------------------------
// Single-pass fused renderer, one block per emitter plane (2048 blocks x 256).
// Prologue (patch -> expanded 13x128 LDS buffer) amortized over 64 KB of
// streaming per block; plain stores (fill kernel reaches 6.6 TB/s this way).
//
// JAX .at[rows,cols].add(patch, mode='drop'): negative indices wrap (+size),
// then still-OOB dropped. Column wrap/drop applied at scatter time; row wrap
// via two-candidate lookup per streamed row.
// ---------------------------------------------------------------------------
__global__ __launch_bounds__(256)
void render_fused_kernel(const float* __restrict__ xyz,       // [B,E,3]
                         const float* __restrict__ n_photons, // [B,E]
                         const float* __restrict__ bg,        // [B,H,W]
                         const float* __restrict__ coeff,     // [D,R,R,4,4,4]
                         float* __restrict__ out)             // [B,E,H,W]
{
    const int be  = blockIdx.x;          // emitter id (0..2047)
    const int b   = be >> 6;             // frame
    const int tid = threadIdx.x;

    __shared__ float s_w[64];            // separable weights pz[a]*py[b]*px[c]
    __shared__ float s_row[R * W];       // expanded patch: [patch_row][image_col]

    // --- emitter parameters (broadcast loads; computed redundantly) ---
    const float x = xyz[be * 3 + 0];
    const float y = xyz[be * 3 + 1];
    const float z = xyz[be * 3 + 2];
    const float nph = n_photons[be];

    const float xf = floorf(x), yf = floorf(y);
    const float dx = x - xf,   dy = y - yf;
    float zc = fminf(fmaxf(z, 0.0f), (float)(D - 1) - 1e-6f);
    const float zf = floorf(zc);
    const int   zi = (int)zf;
    const float dz = zc - zf;

    const int r0 = (int)yf - HALF;       // patch-row 0's image row (may be <0)
    const int c0 = (int)xf - HALF;       // patch-col 0's image col (may be <0)

    // --- stage 1: zero expanded buffer + compute 64 separable weights ---
    #pragma unroll
    for (int i = tid; i < R * W; i += 256) s_row[i] = 0.0f;
    if (tid < 64) {
        const int a  = tid >> 4;
        const int bb = (tid >> 2) & 3;
        const int c  = tid & 3;
        s_w[tid] = pw(dz, a) * pw(dy, bb) * pw(dx, c);
    }
    __syncthreads();

    // --- stage 2: 169 patch pixels; scatter into expanded buffer with
    //     wrap/drop applied to the COLUMN here (row handled at stream time) ---
    if (tid < R * R) {
        const int pr = tid / R;
        const int pc = tid - pr * R;
        const float* cp = coeff + (((size_t)zi * R + pr) * R + pc) * 64;
        float acc = 0.0f;
        #pragma unroll
        for (int k = 0; k < 64; k += 4) {
            const v4f cc = *(const v4f*)(cp + k);
            acc += cc.x * s_w[k + 0];
            acc += cc.y * s_w[k + 1];
            acc += cc.z * s_w[k + 2];
            acc += cc.w * s_w[k + 3];
        }
        int col = c0 + pc;
        if (col < 0) col += W;           // JAX negative-index wrap
        if (col < W)                     // high side: dropped
            s_row[pr * W + col] = acc * nph;
    }
    __syncthreads();

    // --- stage 3: stream the full plane, 16 float4 per thread, write-once ---
    const float* __restrict__ bgp  = bg  + ((size_t)b  << 14);
    float*       __restrict__ outp = out + ((size_t)be << 14);

    #pragma unroll
    for (int j = 0; j < 16; ++j) {
        const int i   = j * 256 + tid;   // float4 index within plane
        const int row = i >> 5;          // 32 float4 per row
        const int col = (i & 31) << 2;
        const size_t off = ((size_t)row << 7) + col;

        v4f v = *(const v4f*)(bgp + off);

        // patch-row lookup with JAX wrap: direct, else wrapped (row>=122)
        int pr = row - r0;
        if (pr < 0 || pr >= R) pr = row - r0 - 128;
        if (pr >= 0 && pr < R) {
            v += *(const v4f*)(s_row + pr * W + col);
        }

        v = v * GAIN + BASELINE;
        *(v4f*)(outp + off) = v;
    }
}

extern "C" void kernel_launch(void* const* d_in, const int* in_sizes, int n_in,
                              void* d_out, int out_size, void* d_ws, size_t ws_size,
                              hipStream_t stream) {
    const float* xyz       = (const float*)d_in[0];  // [B,E,3]
    const float* n_photons = (const float*)d_in[1];  // [B,E]
    const float* bg        = (const float*)d_in[2];  // [B,H,W]
    const float* coeff     = (const float*)d_in[3];  // [D,R,R,4,4,4]
    float* out = (float*)d_out;                      // [B,E,H,W]

    // one block per emitter plane; every output byte written exactly once
    render_fused_kernel<<<dim3(B * E), dim3(256), 0, stream>>>(
        xyz, n_photons, bg, coeff, out);
}